// Round 14
// baseline (544.693 us; speedup 1.0000x reference)
//
#include <hip/hip_runtime.h>

#define TSTEPS 512
#define BATCH  64
#define DIN    256
#define HID    512
#define NCH    8            // chunks per batch row (segmentation)
#define VR     512          // virtual rows = 64 batch x 8 chunks
#define NRB    16           // row-blocks (32 VRs each)
#define NUB    32           // unit-blocks (16 units = 64 gate-cols each)
#define NWG    512          // NRB * NUB
#define NTHR   256
#define HSST   520          // hS row stride (f16): 512+8, 16B-aligned, 2-way banks
#define GST    67           // gateS row stride (f32): odd -> 2-way banks

typedef __attribute__((ext_vector_type(8))) _Float16 f16x8;
typedef __attribute__((ext_vector_type(4))) _Float16 f16x4;
typedef __attribute__((ext_vector_type(4))) float f32x4;
typedef __attribute__((ext_vector_type(2))) float f32x2;

#define MFMA16(A,B,C) __builtin_amdgcn_mfma_f32_16x16x32_f16(A,B,C,0,0,0)
#define ALDU32(p) __hip_atomic_load(const_cast<unsigned*>(p), __ATOMIC_RELAXED, __HIP_MEMORY_SCOPE_AGENT)
#define ASTU32(p,v) __hip_atomic_store((p), (v), __ATOMIC_RELAXED, __HIP_MEMORY_SCOPE_AGENT)

__device__ __forceinline__ float sigm(float x) { return 1.0f / (1.0f + __expf(-x)); }

// 16B loads: _cc = coherent point (LLC, sc0 sc1); _l2 = XCD-L2 coherent (sc0:
// bypass L1, served by the XCD's shared L2 — valid only when producer and
// consumer are runtime-verified to be on the SAME XCD).
__device__ __forceinline__ void gld16_cc(f16x8& d, const void* p) {
  asm volatile("global_load_dwordx4 %0, %1, off sc0 sc1" : "=v"(d) : "v"(p));
}
__device__ __forceinline__ void gld16_l2(f16x8& d, const void* p) {
  asm volatile("global_load_dwordx4 %0, %1, off sc0" : "=v"(d) : "v"(p));
}
// plain cacheable 16B load via asm: result is NOT rematerializable, so the
// compiler must keep it resident in VGPRs (W pinning).
__device__ __forceinline__ void gld16_pin(f16x8& d, const void* p) {
  asm volatile("global_load_dwordx4 %0, %1, off" : "=v"(d) : "v"(p));
}

// one-time: x fp32 -> f16 plane (proven)
__global__ void conv_x(const float* __restrict__ x, _Float16* __restrict__ xh, int n4) {
  int i = blockIdx.x * 256 + threadIdx.x;
  if (i >= n4) return;
  float4 v = reinterpret_cast<const float4*>(x)[i];
  f16x4 o;
  o[0] = (_Float16)v.x; o[1] = (_Float16)v.y; o[2] = (_Float16)v.z; o[3] = (_Float16)v.w;
  *reinterpret_cast<f16x4*>(xh + (size_t)i * 4) = o;
}

// one-time: W -> per-unit-block transposed f16 (proven). cc = unit*4 + gate.
__global__ void w_prep(const float* __restrict__ W,
                       _Float16* __restrict__ WxT, _Float16* __restrict__ WhT) {
  int idx = blockIdx.x * 256 + threadIdx.x;
  if (idx < NUB * 64 * 256) {
    int k = idx & 255, cc = (idx >> 8) & 63, ub = idx >> 14;
    int unit = cc >> 2, g = cc & 3;
    int gcol = g * HID + ub * 16 + unit;
    WxT[idx] = (_Float16)W[k * 2048 + gcol];
  } else if (idx < NUB * 64 * 256 + NUB * 64 * 512) {
    int j = idx - NUB * 64 * 256;
    int k = j & 511, cc = (j >> 9) & 63, ub = j >> 15;
    int unit = cc >> 2, g = cc & 3;
    int gcol = g * HID + ub * 16 + unit;
    WhT[j] = (_Float16)W[(DIN + k) * 2048 + gcol];
  }
}

// segmentation v2: per-row minimize-max chunk length. Internal cut points may
// be ANY reset position (state restarts from 0 there); binary-search minimal
// feasible L, then greedy construct. Block ML = max over its 32 rows.
__global__ void seg_prep(const int* __restrict__ rst, int* __restrict__ tS,
                         int* __restrict__ segLen, int* __restrict__ maxLenB) {
  __shared__ int sMax[NRB];
  const int b = threadIdx.x;                  // 64 threads, 1 block
  if (b < NRB) sMax[b] = 0;
  __syncthreads();
  int lo = (TSTEPS + NCH - 1) / NCH, hi = TSTEPS;
  while (lo < hi) {
    int L = (lo + hi) >> 1;
    int pos = 0; bool ok = false;
    for (int s = 0; s < NCH; ++s) {
      int target = pos + L;
      if (target >= TSTEPS) { ok = true; break; }
      int t = target;
      while (t > pos && rst[t * BATCH + b] == 0) --t;
      if (t == pos) break;                    // no cut available -> infeasible
      pos = t;
    }
    if (ok) hi = L; else lo = L + 1;
  }
  const int L = lo;
  int pos = 0;
  for (int c = 0; c < NCH; ++c) {
    int start = pos, end = pos;
    if (pos < TSTEPS) {
      int target = pos + L;
      if (target >= TSTEPS) end = TSTEPS;
      else { int t = target; while (t > pos && rst[t * BATCH + b] == 0) --t; end = t; }
      pos = end;
    }
    int vr = c * 64 + b;
    tS[vr] = start;
    segLen[vr] = end - start;
    atomicMax(&sMax[c * 2 + (b >> 5)], end - start);
  }
  __syncthreads();
  if (b < NRB) maxLenB[b] = sMax[b];
}

// 512 WGs, 2/CU co-resident (42.1KB LDS, ~200 VGPR, launch_bounds(256,2)).
// Membership: ub = wg>>4, block id rb = ((wg&7)<<1)|((wg>>3)&1); a block's 32
// members share wg&15 => share wg%8 => same XCD under round-robin dispatch.
// XCC_ID is runtime-verified; on failure the block falls back to the proven
// LLC (sc0 sc1) exchange — correctness never assumes the mapping.
__global__ void __launch_bounds__(NTHR, 2)
lstm_persistent(const _Float16* __restrict__ xh,
                const int* __restrict__ rst,
                const float* __restrict__ bias,
                float* __restrict__ out,
                unsigned long long* __restrict__ hb,   // [2][VR][128] u64 (f16 h)
                unsigned* __restrict__ flags,          // [NWG][16] u32 (LLC)
                unsigned* __restrict__ xccb,           // [NWG][16] u32 (LLC)
                const _Float16* __restrict__ WxT,
                const _Float16* __restrict__ WhT,
                const int* __restrict__ tS,
                const int* __restrict__ segLen,
                const int* __restrict__ maxLenB) {
  __shared__ _Float16 hS[32 * HSST];          // 33.3 KB (full 32-row h slab)
  __shared__ float gateS[32 * GST];           // 8.6 KB
  __shared__ float biasS[64];
  __shared__ int uniformS;

  const int tid = threadIdx.x, wg = blockIdx.x;
  const int ub = wg >> 4;
  const int rb = ((wg & 7) << 1) | ((wg >> 3) & 1);
  const int wgbase = wg & 15;                 // shared by all members of rb
  const int vr0 = rb * 32;
  const int lane = tid & 63, wave = tid >> 6;
  const int colA = lane & 15, klo = (lane >> 4) * 8;

  // ---- XCC publish + uniformity check (LLC round; replay-safe) ----
  unsigned myxcc;
  asm volatile("s_getreg_b32 %0, hwreg(HW_REG_XCC_ID)" : "=s"(myxcc));
  if (tid == 0) {
    uniformS = 1;
    ASTU32(xccb + wg * 16, 0x100u | (myxcc & 0xffu));
  }
  __syncthreads();
  if (tid < NUB) {
    int mwg = (tid << 4) | wgbase;
    unsigned v;
    do { v = ALDU32(xccb + mwg * 16); if (!v) __builtin_amdgcn_s_sleep(1); } while (!v);
    if ((v & 0xffu) != (myxcc & 0xffu)) uniformS = 0;
  }

  // ---- prologue: W fragments -> PINNED registers (asm, non-remat) ----
  f16x8 wx[8], wh[16];
  {
    const _Float16* px = WxT + ((size_t)ub * 64 + wave * 16 + colA) * 256 + klo;
    const _Float16* ph = WhT + ((size_t)ub * 64 + wave * 16 + colA) * 512 + klo;
#pragma unroll
    for (int ch = 0; ch < 8; ++ch) gld16_pin(wx[ch], px + ch * 32);
#pragma unroll
    for (int ch = 0; ch < 16; ++ch) gld16_pin(wh[ch], ph + ch * 32);
    asm volatile("s_waitcnt vmcnt(0)" ::: "memory");
    __builtin_amdgcn_sched_barrier(0);
  }
  if (tid < 64) {
    int unit = tid >> 2, g = tid & 3;
    biasS[tid] = bias[g * HID + ub * 16 + unit];
  }

  // MFMA-side per-lane row start times
  int tSr0 = tS[vr0 + colA];
  int tSr1 = tS[vr0 + 16 + colA];

  // cell-side: row crow, units 2p and 2p+1 (intra-wave: p in {2w,2w+1})
  const int crow = tid & 31, p = tid >> 5;
  const int vrc = vr0 + crow, bc = vrc & 63;
  const int tSc_ = tS[vrc], lenc_ = segLen[vrc];
  const int ML = maxLenB[rb];
  float cA = 0.f, cB = 0.f;

  __syncthreads();
  const bool useL2 = (uniformS != 0);
  float bA[4], bB[4];
#pragma unroll
  for (int g = 0; g < 4; ++g) { bA[g] = biasS[8 * p + g]; bB[g] = biasS[8 * p + 4 + g]; }

  const int srow = tid >> 3, ss = tid & 7;    // h-slab staging assignment

  for (int k = 0; k < ML; ++k) {
    // ---- x-part (independent of h): loads + 16 MFMA, BEFORE the poll ----
    f32x4 acc0 = {0.f, 0.f, 0.f, 0.f}, acc1 = {0.f, 0.f, 0.f, 0.f};
    {
      int t0 = tSr0 + k; if (t0 > TSTEPS - 1) t0 = TSTEPS - 1;
      int t1 = tSr1 + k; if (t1 > TSTEPS - 1) t1 = TSTEPS - 1;
      const int b0 = (vr0 + colA) & 63, b1 = (vr0 + 16 + colA) & 63;
      const _Float16* x0 = xh + ((size_t)t0 * BATCH + b0) * DIN + klo;
      const _Float16* x1 = xh + ((size_t)t1 * BATCH + b1) * DIN + klo;
#pragma unroll
      for (int ch = 0; ch < 8; ++ch) {
        f16x8 a0 = *(const f16x8*)(x0 + ch * 32);
        f16x8 a1 = *(const f16x8*)(x1 + ch * 32);
        acc0 = MFMA16(a0, wx[ch], acc0);
        acc1 = MFMA16(a1, wx[ch], acc1);
      }
    }

    if (k) {
      // ---- acquire: poll MY block's 32 producer flags (LLC) ----
      if (tid < NUB) {
        const unsigned tgt = (unsigned)k;
        while (ALDU32(flags + ((tid << 4) | wgbase) * 16) < tgt)
          __builtin_amdgcn_s_sleep(1);
      }
      __syncthreads();
      asm volatile("" ::: "memory");

      // ---- h slab: 8x dwordx4 per thread -> LDS (L2-local if verified) ----
      {
        const char* hbase = (const char*)hb
            + (((size_t)(k & 1) * (VR * 128) + (size_t)(vr0 + srow) * 128) << 3)
            + ss * 16;
        f16x8 hq[8];
        if (useL2) {
#pragma unroll
          for (int j = 0; j < 8; ++j) gld16_l2(hq[j], hbase + j * 128);
        } else {
#pragma unroll
          for (int j = 0; j < 8; ++j) gld16_cc(hq[j], hbase + j * 128);
        }
        asm volatile("s_waitcnt vmcnt(0)" ::: "memory");
        __builtin_amdgcn_sched_barrier(0);     // rule #18
#pragma unroll
        for (int j = 0; j < 8; ++j)
          *(f16x8*)&hS[srow * HSST + ss * 8 + j * 64] = hq[j];
      }
      __syncthreads();                         // slab staged

      // ---- consume: 32 MFMA from LDS + wh regs ----
#pragma unroll
      for (int ch = 0; ch < 16; ++ch) {
        f16x8 a0 = *(const f16x8*)&hS[colA * HSST + ch * 32 + klo];
        f16x8 a1 = *(const f16x8*)&hS[(16 + colA) * HSST + ch * 32 + klo];
        acc0 = MFMA16(a0, wh[ch], acc0);
        acc1 = MFMA16(a1, wh[ch], acc1);
      }
    }

    // ---- stage gates: wave w writes cols 16w..16w+15 (intra-wave w/ cell) ----
#pragma unroll
    for (int rr = 0; rr < 4; ++rr) {
      int row0 = (lane >> 4) * 4 + rr;
      gateS[row0 * GST + wave * 16 + colA]        = acc0[rr];
      gateS[(16 + row0) * GST + wave * 16 + colA] = acc1[rr];
    }

    // ---- cell: row crow, units 2p & 2p+1 (gateS cols 8p..8p+7, same wave) ----
    float hn0, hn1;
    {
      int kidx = tSc_ + k + 1; if (kidx > TSTEPS - 1) kidx = TSTEPS - 1;
      float keep = 1.0f - (float)rst[kidx * BATCH + bc];
      const float* g = &gateS[crow * GST + 8 * p];
      float i0 = sigm(g[0] + bA[0]);
      float t0 = tanhf(g[1] + bA[1]);
      float f0 = sigm(g[2] + bA[2] + 1.0f);    // Haiku forget bias
      float o0 = sigm(g[3] + bA[3]);
      float i1 = sigm(g[4] + bB[0]);
      float t1 = tanhf(g[5] + bB[1]);
      float f1 = sigm(g[6] + bB[2] + 1.0f);
      float o1 = sigm(g[7] + bB[3]);
      float cn0 = f0 * cA + i0 * t0, cn1 = f1 * cB + i1 * t1;
      hn0 = o0 * tanhf(cn0); hn1 = o1 * tanhf(cn1);
      cA = cn0 * keep; cB = cn1 * keep;
      if (k + 1 < ML) {
        union { _Float16 f[2]; unsigned u; } cv;
        cv.f[0] = (_Float16)(hn0 * keep);
        cv.f[1] = (_Float16)(hn1 * keep);
        unsigned* dst = (unsigned*)(hb + (size_t)((k + 1) & 1) * (VR * 128)
                                       + (size_t)vrc * 128) + ub * 8 + p;
        if (useL2)
          asm volatile("global_store_dword %0, %1, off sc0" :: "v"(dst), "v"(cv.u) : "memory");
        else
          ASTU32(dst, cv.u);
      }
    }

    // ---- release: drain h stores (syncthreads emits vmcnt(0)) + LLC flag ----
    __syncthreads();
    if (k + 1 < ML && tid == 0) ASTU32(flags + wg * 16, (unsigned)(k + 1));

    // ---- out store AFTER release: off the critical path ----
    if (k < lenc_) {
      f32x2 o2 = {hn0, hn1};
      *(f32x2*)&out[((size_t)(tSc_ + k) * BATCH + bc) * HID + ub * 16 + 2 * p] = o2;
    }
  }
}

extern "C" void kernel_launch(void* const* d_in, const int* in_sizes, int n_in,
                              void* d_out, int out_size, void* d_ws, size_t ws_size,
                              hipStream_t stream) {
  const float* x   = (const float*)d_in[0];
  const int*   rst = (const int*)d_in[1];
  const float* W   = (const float*)d_in[2];
  const float* b   = (const float*)d_in[3];
  float* out = (float*)d_out;
  char* ws = (char*)d_ws;

  // ws: flags(32K) | xccb(32K) | tS(2K) | segLen(2K) | maxLenB(4K pad) | hb(1M) | xh(16M) | WxT(1M) | WhT(2M)
  unsigned*           flags  = (unsigned*)(ws + 0);
  unsigned*           xccb   = (unsigned*)(ws + 32768);
  int*                tSp    = (int*)(ws + 65536);
  int*                segLen = (int*)(ws + 67584);
  int*                maxLenB= (int*)(ws + 69632);
  unsigned long long* hb     = (unsigned long long*)(ws + 73728);
  _Float16*           xh     = (_Float16*)(ws + 73728 + 1048576);
  _Float16*           WxT    = (_Float16*)(ws + 73728 + 1048576 + 16777216);
  _Float16*           WhT    = (_Float16*)(ws + 73728 + 1048576 + 16777216 + 1048576);

  hipMemsetAsync(ws, 0, 65536, stream);      // flags + xccb (replay-safe)

  int n4 = TSTEPS * BATCH * DIN / 4;
  hipLaunchKernelGGL(conv_x, dim3(n4 / 256), dim3(256), 0, stream, x, xh, n4);
  hipLaunchKernelGGL(w_prep, dim3(6144), dim3(256), 0, stream, W, WxT, WhT);
  hipLaunchKernelGGL(seg_prep, dim3(1), dim3(64), 0, stream, rst, tSp, segLen, maxLenB);

  hipLaunchKernelGGL(lstm_persistent, dim3(NWG), dim3(NTHR), 0, stream,
                     xh, rst, b, out, hb, flags, xccb, WxT, WhT, tSp, segLen, maxLenB);
}